// Round 2
// baseline (34271.875 us; speedup 1.0000x reference)
//
#include <hip/hip_runtime.h>
#include <hip/hip_bf16.h>

// Problem constants (S,B,D,H,T) = (4,512,256,1024,50)
#define S_ 4
#define B_ 512
#define D_ 256
#define H_ 1024
#define T_ 50
#define M_ (S_*B_)   // 2048 rows total

#define LDH (H_ + 8)   // padded LDS row stride for h1/h2 (bf16 elems)
#define LDU (D_ + 8)   // padded LDS row stride for u

typedef __attribute__((ext_vector_type(8))) __bf16 bf16x8;
typedef __attribute__((ext_vector_type(4))) float  f32x4;

// NaN-free fast tanh: saturates to +/-1, ~1e-6 abs error (<< bf16 eps)
__device__ __forceinline__ float fast_tanh(float x) {
  const float e = __expf(2.f * x);
  return 1.f - 2.f / (e + 1.f);
}

// non-temporal output store (keep 100MB traj stream out of L2 so the cyclic
// 3MB weight working set stays resident per-XCD)
__device__ __forceinline__ void store_out(void* out, size_t off, float v,
                                          int ofl) {
  if (ofl) {
    __builtin_nontemporal_store(v, (float*)out + off);
  } else {
    const unsigned short u =
        __builtin_bit_cast(unsigned short, __float2bfloat16(v));
    __builtin_nontemporal_store(u, (unsigned short*)out + off);
  }
}

// ---------------------------------------------------------------------------
// Runtime dtype detection + dt table + reg_state zeros.
//   flags[0] = weights/first_point/output are f32 (1) or bf16 (0)
//   flags[1] = time grid is f32 (1) or bf16 (0)
// ---------------------------------------------------------------------------
__global__ void detect_k(const void* t_raw, const void* w2_raw,
                         float* dts, int* flags, void* out) {
  __shared__ int cnt;
  const int l = threadIdx.x;           // 64 threads, 1 block
  if (l == 0) cnt = 0;
  __syncthreads();
  const unsigned short* u = (const unsigned short*)w2_raw;
  int c = 0;
  #pragma unroll
  for (int j = 0; j < 4; ++j) {
    const unsigned short v = u[l * 4 + j];
    const unsigned e = (v >> 7) & 0xFF;          // bf16 exponent field
    if (e >= 128) c++;                            // |x| >= 2.0 or NaN/Inf
  }
  atomicAdd(&cnt, c);
  __syncthreads();
  const unsigned tw0 = *(const unsigned*)t_raw;
  const int t_is_f32 = (tw0 == 0u) ? 1 : 0;
  const int w_is_f32 = (cnt > 16) ? 1 : 0;
  if (l == 0) { flags[0] = w_is_f32; flags[1] = t_is_f32; }
  if (l < T_ - 1) {
    float t0, t1;
    if (t_is_f32) {
      const float* tf = (const float*)t_raw;
      t0 = tf[l]; t1 = tf[l + 1];
    } else {
      const __hip_bfloat16* tb = (const __hip_bfloat16*)t_raw;
      t0 = __bfloat162float(tb[l]); t1 = __bfloat162float(tb[l + 1]);
    }
    dts[l] = t1 - t0;
  }
  if (l < S_) {   // reg_state = 0
    const size_t ro = (size_t)M_ * T_ * D_ + l;
    if (w_is_f32) ((float*)out)[ro] = 0.f;
    else          ((__hip_bfloat16*)out)[ro] = __float2bfloat16(0.f);
  }
}

// ---------------------------------------------------------------------------
// transpose to bf16: dst[N][K] = bf16(src[K][N]); src dtype per flags[0]
// ---------------------------------------------------------------------------
__global__ void transpose_k(const void* __restrict__ src,
                            __hip_bfloat16* __restrict__ dst, int K, int N,
                            const int* __restrict__ flags) {
  __shared__ __hip_bfloat16 tile[32][33];
  const int f32 = flags[0];
  const int tx = threadIdx.x, ty = threadIdx.y;
  const int nb = blockIdx.x * 32, kb = blockIdx.y * 32;
  #pragma unroll
  for (int j = 0; j < 32; j += 8) {
    const size_t si = (size_t)(kb + ty + j) * N + nb + tx;
    tile[ty + j][tx] = f32 ? __float2bfloat16(((const float*)src)[si])
                           : ((const __hip_bfloat16*)src)[si];
  }
  __syncthreads();
  #pragma unroll
  for (int j = 0; j < 32; j += 8)
    dst[(size_t)(nb + ty + j) * K + kb + tx] = tile[tx][ty + j];
}

// ---------------------------------------------------------------------------
// biases -> fp32 workspace arrays
// ---------------------------------------------------------------------------
__global__ void prep_bias_k(const void* b1r, const void* b2r, const void* b3r,
                            float* bf1, float* bf2, float* bf3,
                            const int* flags) {
  const int i = blockIdx.x * 256 + threadIdx.x;   // H_ threads
  const int f32 = flags[0];
  bf1[i] = f32 ? ((const float*)b1r)[i]
               : __bfloat162float(((const __hip_bfloat16*)b1r)[i]);
  bf2[i] = f32 ? ((const float*)b2r)[i]
               : __bfloat162float(((const __hip_bfloat16*)b2r)[i]);
  if (i < D_)
    bf3[i] = f32 ? ((const float*)b3r)[i]
                 : __bfloat162float(((const __hip_bfloat16*)b3r)[i]);
}

// ---------------------------------------------------------------------------
// pack Wt[N][K] (row-major bf16) into per-wave fragment-major stream:
//   block index p = (w*KT + kk)*TPW + nt   (w = wave 0..7, KT = K/32)
//   within block: lane*16B = MFMA B-fragment of tile (n0=(w*TPW+nt)*16, k0=kk*32)
//     lane elems j: Wt[n0 + (lane&15)][kk*32 + (lane>>4)*8 + j]
// One thread copies one 16B fragment; grid sized exactly to N*K/8 threads.
// ---------------------------------------------------------------------------
__global__ void pack_k(const __hip_bfloat16* __restrict__ Wt,
                       __hip_bfloat16* __restrict__ P, int K, int TPW) {
  const int tid = blockIdx.x * 256 + threadIdx.x;
  const int lane = tid & 63;
  const int p = tid >> 6;
  const int KT = K >> 5;
  const int nt = p % TPW;
  const int kk = (p / TPW) % KT;
  const int w  = p / (TPW * KT);
  const int n  = (w * TPW + nt) * 16 + (lane & 15);
  const int ko = kk * 32 + (lane >> 4) * 8;
  *(bf16x8*)&P[(size_t)tid * 8] = *(const bf16x8*)&Wt[(size_t)n * K + ko];
}

// ---------------------------------------------------------------------------
// Per-wave GEMM over the packed weight stream, DEPTH-deep register pipeline.
//   out[16 x TPW*16] tile for this wave; A = 16 rows in LDS (row stride LDA).
//   B fragments stream linearly from global (packed). DEPTH slices of B (and
//   A) are kept in flight so L2/LLC latency hides under the MFMA of older
//   slices. All array indices are compile-time after unroll (no scratch).
// ---------------------------------------------------------------------------
template <int KT, int TPW, int LDA, int DEPTH>
__device__ __forceinline__ void gemm_wave(const __hip_bfloat16* lA,
                                          const __hip_bfloat16* BpW,
                                          int l16, int quad, f32x4* acc) {
  const bf16x8* __restrict__ b = (const bf16x8*)BpW + (quad * 16 + l16);
  const __hip_bfloat16* arow = &lA[l16 * LDA + quad * 8];
  bf16x8 bb[DEPTH][TPW];
  bf16x8 aa[DEPTH];
  #pragma unroll
  for (int p = 0; p < DEPTH - 1; p++) {
    if (p < KT) {
      aa[p] = *(const bf16x8*)(arow + p * 32);
      #pragma unroll
      for (int nt = 0; nt < TPW; nt++)
        bb[p][nt] = b[(p * TPW + nt) * 64];
    }
  }
  #pragma unroll
  for (int kk = 0; kk < KT; kk++) {
    const int pre = kk + DEPTH - 1;
    if (pre < KT) {
      aa[pre % DEPTH] = *(const bf16x8*)(arow + pre * 32);
      #pragma unroll
      for (int nt = 0; nt < TPW; nt++)
        bb[pre % DEPTH][nt] = b[(pre * TPW + nt) * 64];
    }
    #pragma unroll
    for (int nt = 0; nt < TPW; nt++)
      acc[nt] = __builtin_amdgcn_mfma_f32_16x16x32_bf16(
          aa[kk % DEPTH], bb[kk % DEPTH][nt], acc[nt], 0, 0, 0);
  }
}

// ---------------------------------------------------------------------------
// Persistent ODE kernel: 128 blocks x 16 rows, 512 threads (8 waves).
// Each block integrates its 16 rows through all T-1 RK4 steps.
//   - u/h1/h2 activations in LDS (bf16, padded rows)
//   - y, accb RK4 state in registers (MFMA C-layout positions are static)
//   - weights streamed from L2 each stage via packed fragment-major layout
//   - 3 __syncthreads per stage, zero inter-block communication
// launch_bounds(512,2): 2 waves/SIMD -> 256-VGPR budget for the deep pipeline.
// LDS padded >80KB so at most 1 block/CU (blocks spread over 128 distinct CUs).
// ---------------------------------------------------------------------------
__global__ __launch_bounds__(512, 2) void ode_k(
    const void* __restrict__ fp_raw,
    const __hip_bfloat16* __restrict__ W1p,
    const __hip_bfloat16* __restrict__ W2p,
    const __hip_bfloat16* __restrict__ W3p,
    const float* __restrict__ bf1, const float* __restrict__ bf2,
    const float* __restrict__ bf3, const float* __restrict__ dts,
    const int* __restrict__ flags, void* __restrict__ out) {
  __shared__ __hip_bfloat16 uA[16 * LDU];
  __shared__ __hip_bfloat16 h1s[16 * LDH];
  __shared__ __hip_bfloat16 h2s[16 * LDH];
  __shared__ float lds_guard[2048];   // pushes LDS past 80KB -> 1 block/CU

  const int tid = threadIdx.x;
  const int wave = tid >> 6, lane = tid & 63;
  const int l16 = lane & 15, quad = lane >> 4;
  const int m0 = blockIdx.x * 16;
  const int rb = quad * 4;                 // this lane's C-layout row base
  const int ofl = flags[0];
  if (ofl == 31337)                        // never true; keeps lds_guard live
    ((volatile float*)lds_guard)[tid & 2047] = 1.f;

  // per-wave packed weight slice bases (bf16 elems): wave slice = KT*TPW*512
  const __hip_bfloat16* W1w = W1p + (size_t)wave * (8  * 8 * 512);
  const __hip_bfloat16* W2w = W2p + (size_t)wave * (32 * 8 * 512);
  const __hip_bfloat16* W3w = W3p + (size_t)wave * (32 * 2 * 512);

  // bias registers (match epilogue column mapping)
  float b1r[8], b2r[8], b3r[2];
  #pragma unroll
  for (int nt = 0; nt < 8; nt++) {
    b1r[nt] = bf1[wave * 128 + nt * 16 + l16];
    b2r[nt] = bf2[wave * 128 + nt * 16 + l16];
  }
  #pragma unroll
  for (int nt = 0; nt < 2; nt++) b3r[nt] = bf3[wave * 32 + nt * 16 + l16];

  // RK4 state in registers at this lane's L3 C-layout positions:
  //   (m = m0 + rb + r, d = wave*32 + nt*16 + l16)
  float yreg[2][4], ab[2][4];
  #pragma unroll
  for (int nt = 0; nt < 2; nt++) {
    const int d = wave * 32 + nt * 16 + l16;
    #pragma unroll
    for (int r = 0; r < 4; r++) {
      const int m = m0 + rb + r;
      const size_t si = (size_t)m * D_ + d;
      const float v = ofl ? ((const float*)fp_raw)[si]
                          : __bfloat162float(((const __hip_bfloat16*)fp_raw)[si]);
      yreg[nt][r] = v;
      ab[nt][r] = 0.f;
      uA[(rb + r) * LDU + d] = __float2bfloat16(v);   // stage0 u = y
      store_out(out, ((size_t)m * T_) * D_ + d, v, ofl);  // traj[t=0] = y
    }
  }
  __syncthreads();

  #pragma unroll 1
  for (int t = 0; t < T_ - 1; ++t) {
    const float dtv = dts[t];
    #pragma unroll 1
    for (int st4 = 0; st4 < 4; ++st4) {
      // ---- L1: h1 = tanh(u @ W1 + b1), K = 256 ----
      {
        f32x4 acc[8];
        #pragma unroll
        for (int i = 0; i < 8; i++) acc[i] = f32x4{0.f, 0.f, 0.f, 0.f};
        gemm_wave<8, 8, LDU, 3>(uA, W1w, l16, quad, acc);
        #pragma unroll
        for (int nt = 0; nt < 8; nt++) {
          const int col = wave * 128 + nt * 16 + l16;
          #pragma unroll
          for (int r = 0; r < 4; r++)
            h1s[(rb + r) * LDH + col] =
                __float2bfloat16(fast_tanh(acc[nt][r] + b1r[nt]));
        }
      }
      __syncthreads();
      // ---- L2: h2 = tanh(h1 @ W2 + b2), K = 1024 ----
      {
        f32x4 acc[8];
        #pragma unroll
        for (int i = 0; i < 8; i++) acc[i] = f32x4{0.f, 0.f, 0.f, 0.f};
        gemm_wave<32, 8, LDH, 3>(h1s, W2w, l16, quad, acc);
        #pragma unroll
        for (int nt = 0; nt < 8; nt++) {
          const int col = wave * 128 + nt * 16 + l16;
          #pragma unroll
          for (int r = 0; r < 4; r++)
            h2s[(rb + r) * LDH + col] =
                __float2bfloat16(fast_tanh(acc[nt][r] + b2r[nt]));
        }
      }
      __syncthreads();
      // ---- L3: k = h2 @ W3 + b3, K = 1024; RK4 bookkeeping in registers ----
      {
        f32x4 acc[2];
        #pragma unroll
        for (int i = 0; i < 2; i++) acc[i] = f32x4{0.f, 0.f, 0.f, 0.f};
        gemm_wave<32, 2, LDH, 4>(h2s, W3w, l16, quad, acc);
        #pragma unroll
        for (int nt = 0; nt < 2; nt++) {
          const int d = wave * 32 + nt * 16 + l16;
          #pragma unroll
          for (int r = 0; r < 4; r++) {
            const float kv = acc[nt][r] + b3r[nt];
            float uv;
            if (st4 == 0) {
              ab[nt][r] = kv;            uv = yreg[nt][r] + 0.5f * dtv * kv;
            } else if (st4 == 1) {
              ab[nt][r] += 2.f * kv;     uv = yreg[nt][r] + 0.5f * dtv * kv;
            } else if (st4 == 2) {
              ab[nt][r] += 2.f * kv;     uv = yreg[nt][r] + dtv * kv;
            } else {
              const float yn =
                  yreg[nt][r] + (dtv * (1.f / 6.f)) * (ab[nt][r] + kv);
              yreg[nt][r] = yn;
              uv = yn;                   // next timestep stage0: u = y
              store_out(out, ((size_t)(m0 + rb + r) * T_ + (t + 1)) * D_ + d,
                        yn, ofl);
            }
            uA[(rb + r) * LDU + d] = __float2bfloat16(uv);
          }
        }
      }
      __syncthreads();
    }
  }
}

// ---------------------------------------------------------------------------
extern "C" void kernel_launch(void* const* d_in, const int* in_sizes, int n_in,
                              void* d_out, int out_size, void* d_ws, size_t ws_size,
                              hipStream_t stream) {
  const void* fp   = d_in[0];
  const void* tarr = d_in[1];
  const void* W1   = d_in[2];
  const void* b1   = d_in[3];
  const void* W2   = d_in[4];
  const void* b2   = d_in[5];
  const void* W3   = d_in[6];
  const void* b3   = d_in[7];

  // workspace carve (~6.2 MB total, all bases 16B-aligned)
  char* ws = (char*)d_ws;
  __hip_bfloat16* W1p = (__hip_bfloat16*)ws; ws += (size_t)H_ * D_ * 2;
  __hip_bfloat16* W2p = (__hip_bfloat16*)ws; ws += (size_t)H_ * H_ * 2;
  __hip_bfloat16* W3p = (__hip_bfloat16*)ws; ws += (size_t)D_ * H_ * 2;
  __hip_bfloat16* W1t = (__hip_bfloat16*)ws; ws += (size_t)H_ * D_ * 2;
  __hip_bfloat16* W2t = (__hip_bfloat16*)ws; ws += (size_t)H_ * H_ * 2;
  __hip_bfloat16* W3t = (__hip_bfloat16*)ws; ws += (size_t)D_ * H_ * 2;
  float* bf1  = (float*)ws;                  ws += (size_t)H_ * 4;
  float* bf2  = (float*)ws;                  ws += (size_t)H_ * 4;
  float* bf3  = (float*)ws;                  ws += (size_t)D_ * 4;
  float* dts  = (float*)ws;                  ws += 64 * 4;
  int*   flags= (int*)ws;                    ws += 64 * 4;

  detect_k<<<1, 64, 0, stream>>>(tarr, W2, dts, flags, d_out);
  dim3 tb(32, 8);
  transpose_k<<<dim3(H_ / 32, D_ / 32), tb, 0, stream>>>(W1, W1t, D_, H_, flags);
  transpose_k<<<dim3(H_ / 32, H_ / 32), tb, 0, stream>>>(W2, W2t, H_, H_, flags);
  transpose_k<<<dim3(D_ / 32, H_ / 32), tb, 0, stream>>>(W3, W3t, H_, D_, flags);
  prep_bias_k<<<H_ / 256, 256, 0, stream>>>(b1, b2, b3, bf1, bf2, bf3, flags);
  pack_k<<<(H_ * D_ / 8) / 256, 256, 0, stream>>>(W1t, W1p, D_, 8);
  pack_k<<<(H_ * H_ / 8) / 256, 256, 0, stream>>>(W2t, W2p, H_, 8);
  pack_k<<<(D_ * H_ / 8) / 256, 256, 0, stream>>>(W3t, W3p, H_, 2);
  ode_k<<<M_ / 16, 512, 0, stream>>>(fp, W1p, W2p, W3p, bf1, bf2, bf3,
                                     dts, flags, d_out);
}

// Round 3
// 8833.533 us; speedup vs baseline: 3.8797x; 3.8797x over previous
//
#include <hip/hip_runtime.h>
#include <hip/hip_bf16.h>

// Problem constants (S,B,D,H,T) = (4,512,256,1024,50)
#define S_ 4
#define B_ 512
#define D_ 256
#define H_ 1024
#define T_ 50
#define M_ (S_*B_)   // 2048 rows total

#define LDH (H_ + 8)   // padded LDS row stride for h1/h2 (bf16 elems)
#define LDU (D_ + 8)   // padded LDS row stride for u

typedef __attribute__((ext_vector_type(8))) __bf16 bf16x8;
typedef __attribute__((ext_vector_type(4))) float  f32x4;

#define MFMA16(a, b, c) __builtin_amdgcn_mfma_f32_16x16x32_bf16(a, b, c, 0, 0, 0)
#define VM4() asm volatile("s_waitcnt vmcnt(4)" ::: "memory")
#define VM0() asm volatile("s_waitcnt vmcnt(0)" ::: "memory")
#define SB0() __builtin_amdgcn_sched_barrier(0)
#define BARRIER() do { SB0(); __builtin_amdgcn_s_barrier(); SB0(); } while (0)

__device__ __forceinline__ void gld16(const void* g, void* l) {
  // async global->LDS, 16B per lane. LDS dest must be wave-uniform base (+lane*16 by HW).
  __builtin_amdgcn_global_load_lds(
      (const __attribute__((address_space(1))) void*)g,
      (__attribute__((address_space(3))) void*)l, 16, 0, 0);
}

// NaN-free fast tanh: saturates to +/-1, ~1e-6 abs error (<< bf16 eps)
__device__ __forceinline__ float fast_tanh(float x) {
  const float e = __expf(2.f * x);
  return 1.f - 2.f / (e + 1.f);
}

// non-temporal output store (keep 100MB traj stream from evicting the 3MB
// cyclic weight working set out of the per-XCD L2s)
__device__ __forceinline__ void store_out(void* out, size_t off, float v,
                                          int ofl) {
  if (ofl) {
    __builtin_nontemporal_store(v, (float*)out + off);
  } else {
    const unsigned short u =
        __builtin_bit_cast(unsigned short, __float2bfloat16(v));
    __builtin_nontemporal_store(u, (unsigned short*)out + off);
  }
}

// ---------------------------------------------------------------------------
// Runtime dtype detection + dt table + reg_state zeros.
//   flags[0] = weights/first_point/output are f32 (1) or bf16 (0)
//   flags[1] = time grid is f32 (1) or bf16 (0)
// ---------------------------------------------------------------------------
__global__ void detect_k(const void* t_raw, const void* w2_raw,
                         float* dts, int* flags, void* out) {
  __shared__ int cnt;
  const int l = threadIdx.x;           // 64 threads, 1 block
  if (l == 0) cnt = 0;
  __syncthreads();
  const unsigned short* u = (const unsigned short*)w2_raw;
  int c = 0;
  #pragma unroll
  for (int j = 0; j < 4; ++j) {
    const unsigned short v = u[l * 4 + j];
    const unsigned e = (v >> 7) & 0xFF;          // bf16 exponent field
    if (e >= 128) c++;                            // |x| >= 2.0 or NaN/Inf
  }
  atomicAdd(&cnt, c);
  __syncthreads();
  const unsigned tw0 = *(const unsigned*)t_raw;
  const int t_is_f32 = (tw0 == 0u) ? 1 : 0;
  const int w_is_f32 = (cnt > 16) ? 1 : 0;
  if (l == 0) { flags[0] = w_is_f32; flags[1] = t_is_f32; }
  if (l < T_ - 1) {
    float t0, t1;
    if (t_is_f32) {
      const float* tf = (const float*)t_raw;
      t0 = tf[l]; t1 = tf[l + 1];
    } else {
      const __hip_bfloat16* tb = (const __hip_bfloat16*)t_raw;
      t0 = __bfloat162float(tb[l]); t1 = __bfloat162float(tb[l + 1]);
    }
    dts[l] = t1 - t0;
  }
  if (l < S_) {   // reg_state = 0
    const size_t ro = (size_t)M_ * T_ * D_ + l;
    if (w_is_f32) ((float*)out)[ro] = 0.f;
    else          ((__hip_bfloat16*)out)[ro] = __float2bfloat16(0.f);
  }
}

// ---------------------------------------------------------------------------
// transpose to bf16: dst[N][K] = bf16(src[K][N]); src dtype per flags[0]
// ---------------------------------------------------------------------------
__global__ void transpose_k(const void* __restrict__ src,
                            __hip_bfloat16* __restrict__ dst, int K, int N,
                            const int* __restrict__ flags) {
  __shared__ __hip_bfloat16 tile[32][33];
  const int f32 = flags[0];
  const int tx = threadIdx.x, ty = threadIdx.y;
  const int nb = blockIdx.x * 32, kb = blockIdx.y * 32;
  #pragma unroll
  for (int j = 0; j < 32; j += 8) {
    const size_t si = (size_t)(kb + ty + j) * N + nb + tx;
    tile[ty + j][tx] = f32 ? __float2bfloat16(((const float*)src)[si])
                           : ((const __hip_bfloat16*)src)[si];
  }
  __syncthreads();
  #pragma unroll
  for (int j = 0; j < 32; j += 8)
    dst[(size_t)(nb + ty + j) * K + kb + tx] = tile[tx][ty + j];
}

// ---------------------------------------------------------------------------
// biases -> fp32 workspace arrays
// ---------------------------------------------------------------------------
__global__ void prep_bias_k(const void* b1r, const void* b2r, const void* b3r,
                            float* bf1, float* bf2, float* bf3,
                            const int* flags) {
  const int i = blockIdx.x * 256 + threadIdx.x;   // H_ threads
  const int f32 = flags[0];
  bf1[i] = f32 ? ((const float*)b1r)[i]
               : __bfloat162float(((const __hip_bfloat16*)b1r)[i]);
  bf2[i] = f32 ? ((const float*)b2r)[i]
               : __bfloat162float(((const __hip_bfloat16*)b2r)[i]);
  if (i < D_)
    bf3[i] = f32 ? ((const float*)b3r)[i]
                 : __bfloat162float(((const __hip_bfloat16*)b3r)[i]);
}

// ---------------------------------------------------------------------------
// pack Wt[N][K] (row-major bf16) into CHUNK-major fragment stream.
// Chunk = 32KB = 2048 fragments of 16B = per-wave 4 MFMA B-fragments.
// Stream frag index = c*2048 + w*256 + ntl*64 + lane, where
//   TPW==8: chunk c covers (kk = c/2, tiles nt = (c&1)*4 + ntl)
//   TPW==2: chunk c covers (kk = 2c + ntl/2, nt = ntl&1)
// Fragment content (per MFMA B layout): elems j of lane:
//   Wt[(w*TPW+nt)*16 + (lane&15)][kk*32 + (lane>>4)*8 + j]
// LDS-linear == stream-linear, matching global_load_lds's uniform-base+lane*16.
// ---------------------------------------------------------------------------
__global__ void pack_k(const __hip_bfloat16* __restrict__ Wt,
                       __hip_bfloat16* __restrict__ P, int K, int TPW) {
  const int frag = blockIdx.x * 256 + threadIdx.x;   // one 16B fragment each
  const int lane = frag & 63;
  const int c    = frag >> 11;
  const int q    = frag & 2047;
  const int w    = q >> 8;
  const int ntl  = (q >> 6) & 3;
  int kk, nt;
  if (TPW == 8) { kk = c >> 1; nt = (c & 1) * 4 + ntl; }
  else          { kk = c * 2 + (ntl >> 1); nt = ntl & 1; }
  const int n  = (w * TPW + nt) * 16 + (lane & 15);
  const int ko = kk * 32 + (lane >> 4) * 8;
  *(bf16x8*)&P[(size_t)frag * 8] = *(const bf16x8*)&Wt[(size_t)n * K + ko];
}

// ---------------------------------------------------------------------------
// Streaming GEMM: B weights stream chunk-by-chunk (32KB) through a 2-deep LDS
// ring via global_load_lds with COUNTED vmcnt (T3+T4): loads for chunk c+1
// stay in flight across the barrier while chunk c is consumed. 64KB/CU in
// flight covers the ~400ns L2/LLC latency -> BW-bound, not latency-bound.
// Per chunk: issue(c+1); vmcnt(4); barrier; consume; barrier (buf-reuse guard).
// All barriers are block-uniform control flow.
// ---------------------------------------------------------------------------
template <int KT, int TPW, int LDA>
__device__ __forceinline__ void gemm_stream(
    const __hip_bfloat16* __restrict__ lA,
    const __hip_bfloat16* __restrict__ gB,
    __hip_bfloat16* __restrict__ Bst,     // 2 x 32KB LDS ring
    const int wave, const int lane, const int l16, const int quad,
    f32x4* acc) {
  constexpr int NCH = (KT * TPW) / 4;     // chunks (per-wave 4 frags each)
  const char* gbase = (const char*)gB + wave * 1024 + (size_t)lane * 16;
  char* lbase = (char*)Bst + wave * 1024;          // wave-uniform LDS base
  auto issue = [&](int c) {
    const char* g = gbase + (size_t)c * 32768;
    char* l = lbase + (c & 1) * 32768;
    #pragma unroll
    for (int j = 0; j < 4; ++j) gld16(g + j * 8192, l + j * 8192);
  };
  const __hip_bfloat16* bp0 = Bst + wave * 2048 + lane * 8;
  issue(0);
  if constexpr (TPW == 8) {
    #pragma unroll 1
    for (int kk = 0; kk < KT - 1; ++kk) {
      const bf16x8 aF = *(const bf16x8*)&lA[l16 * LDA + kk * 32 + quad * 8];
      issue(2 * kk + 1);
      VM4(); BARRIER();
      acc[0] = MFMA16(aF, *(const bf16x8*)&bp0[0],    acc[0]);
      acc[1] = MFMA16(aF, *(const bf16x8*)&bp0[512],  acc[1]);
      acc[2] = MFMA16(aF, *(const bf16x8*)&bp0[1024], acc[2]);
      acc[3] = MFMA16(aF, *(const bf16x8*)&bp0[1536], acc[3]);
      BARRIER();
      issue(2 * kk + 2);
      VM4(); BARRIER();
      {
        const __hip_bfloat16* bp = bp0 + 16384;
        acc[4] = MFMA16(aF, *(const bf16x8*)&bp[0],    acc[4]);
        acc[5] = MFMA16(aF, *(const bf16x8*)&bp[512],  acc[5]);
        acc[6] = MFMA16(aF, *(const bf16x8*)&bp[1024], acc[6]);
        acc[7] = MFMA16(aF, *(const bf16x8*)&bp[1536], acc[7]);
      }
      BARRIER();
    }
    {  // tail kk = KT-1
      const bf16x8 aF =
          *(const bf16x8*)&lA[l16 * LDA + (KT - 1) * 32 + quad * 8];
      issue(2 * KT - 1);
      VM4(); BARRIER();
      acc[0] = MFMA16(aF, *(const bf16x8*)&bp0[0],    acc[0]);
      acc[1] = MFMA16(aF, *(const bf16x8*)&bp0[512],  acc[1]);
      acc[2] = MFMA16(aF, *(const bf16x8*)&bp0[1024], acc[2]);
      acc[3] = MFMA16(aF, *(const bf16x8*)&bp0[1536], acc[3]);
      BARRIER();
      VM0(); BARRIER();
      {
        const __hip_bfloat16* bp = bp0 + 16384;
        acc[4] = MFMA16(aF, *(const bf16x8*)&bp[0],    acc[4]);
        acc[5] = MFMA16(aF, *(const bf16x8*)&bp[512],  acc[5]);
        acc[6] = MFMA16(aF, *(const bf16x8*)&bp[1024], acc[6]);
        acc[7] = MFMA16(aF, *(const bf16x8*)&bp[1536], acc[7]);
      }
      BARRIER();
    }
  } else {  // TPW == 2 (L3): chunk c covers kk = 2c, 2c+1, 2 tiles each
    #pragma unroll 1
    for (int c = 0; c < NCH - 1; ++c) {
      issue(c + 1);
      VM4(); BARRIER();
      {
        const __hip_bfloat16* bp = bp0 + (c & 1) * 16384;
        const bf16x8 a0 =
            *(const bf16x8*)&lA[l16 * LDA + (c * 2) * 32 + quad * 8];
        acc[0] = MFMA16(a0, *(const bf16x8*)&bp[0],   acc[0]);
        acc[1] = MFMA16(a0, *(const bf16x8*)&bp[512], acc[1]);
        const bf16x8 a1 =
            *(const bf16x8*)&lA[l16 * LDA + (c * 2 + 1) * 32 + quad * 8];
        acc[0] = MFMA16(a1, *(const bf16x8*)&bp[1024], acc[0]);
        acc[1] = MFMA16(a1, *(const bf16x8*)&bp[1536], acc[1]);
      }
      BARRIER();
    }
    {  // tail c = NCH-1 (odd -> buf1)
      VM0(); BARRIER();
      const __hip_bfloat16* bp = bp0 + 16384;
      const bf16x8 a0 =
          *(const bf16x8*)&lA[l16 * LDA + ((NCH - 1) * 2) * 32 + quad * 8];
      acc[0] = MFMA16(a0, *(const bf16x8*)&bp[0],   acc[0]);
      acc[1] = MFMA16(a0, *(const bf16x8*)&bp[512], acc[1]);
      const bf16x8 a1 =
          *(const bf16x8*)&lA[l16 * LDA + ((NCH - 1) * 2 + 1) * 32 + quad * 8];
      acc[0] = MFMA16(a1, *(const bf16x8*)&bp[1024], acc[0]);
      acc[1] = MFMA16(a1, *(const bf16x8*)&bp[1536], acc[1]);
      BARRIER();
    }
  }
}

// ---------------------------------------------------------------------------
// Persistent ODE kernel: 128 blocks x 16 rows, 512 threads (8 waves).
// Each block integrates its 16 rows through all T-1 RK4 steps.
//   - u/h1/h2 activations in LDS (bf16, padded rows)
//   - y, accb RK4 state in registers (MFMA C-layout positions are static)
//   - weights streamed per stage through a 2-deep 32KB LDS ring (counted vmcnt)
//   - zero inter-block communication
// LDS 137KB -> exactly 1 block/CU; 8 waves = 2/SIMD.
// ---------------------------------------------------------------------------
__global__ __launch_bounds__(512, 2) void ode_k(
    const void* __restrict__ fp_raw,
    const __hip_bfloat16* __restrict__ W1p,
    const __hip_bfloat16* __restrict__ W2p,
    const __hip_bfloat16* __restrict__ W3p,
    const float* __restrict__ bf1, const float* __restrict__ bf2,
    const float* __restrict__ bf3, const float* __restrict__ dts,
    const int* __restrict__ flags, void* __restrict__ out) {
  __shared__ __hip_bfloat16 uA[16 * LDU];       //  8.2 KB
  __shared__ __hip_bfloat16 h1s[16 * LDH];      // 32.3 KB
  __shared__ __hip_bfloat16 h2s[16 * LDH];      // 32.3 KB
  __shared__ __hip_bfloat16 Bst[2 * 16384];     // 64   KB ring

  const int tid = threadIdx.x;
  const int wave = tid >> 6, lane = tid & 63;
  const int l16 = lane & 15, quad = lane >> 4;
  const int m0 = blockIdx.x * 16;
  const int rb = quad * 4;                 // this lane's C-layout row base
  const int ofl = flags[0];

  // bias registers (match epilogue column mapping)
  float b1r[8], b2r[8], b3r[2];
  #pragma unroll
  for (int nt = 0; nt < 8; nt++) {
    b1r[nt] = bf1[wave * 128 + nt * 16 + l16];
    b2r[nt] = bf2[wave * 128 + nt * 16 + l16];
  }
  #pragma unroll
  for (int nt = 0; nt < 2; nt++) b3r[nt] = bf3[wave * 32 + nt * 16 + l16];

  // RK4 state in registers at this lane's L3 C-layout positions:
  //   (m = m0 + rb + r, d = wave*32 + nt*16 + l16)
  float yreg[2][4], ab[2][4];
  #pragma unroll
  for (int nt = 0; nt < 2; nt++) {
    const int d = wave * 32 + nt * 16 + l16;
    #pragma unroll
    for (int r = 0; r < 4; r++) {
      const int m = m0 + rb + r;
      const size_t si = (size_t)m * D_ + d;
      const float v = ofl ? ((const float*)fp_raw)[si]
                          : __bfloat162float(((const __hip_bfloat16*)fp_raw)[si]);
      yreg[nt][r] = v;
      ab[nt][r] = 0.f;
      uA[(rb + r) * LDU + d] = __float2bfloat16(v);   // stage0 u = y
      store_out(out, ((size_t)m * T_) * D_ + d, v, ofl);  // traj[t=0] = y
    }
  }
  __syncthreads();

  #pragma unroll 1
  for (int t = 0; t < T_ - 1; ++t) {
    const float dtv = dts[t];
    #pragma unroll 1
    for (int st4 = 0; st4 < 4; ++st4) {
      // ---- L1: h1 = tanh(u @ W1 + b1), K = 256 ----
      {
        f32x4 acc[8];
        #pragma unroll
        for (int i = 0; i < 8; i++) acc[i] = f32x4{0.f, 0.f, 0.f, 0.f};
        gemm_stream<8, 8, LDU>(uA, W1p, Bst, wave, lane, l16, quad, acc);
        #pragma unroll
        for (int nt = 0; nt < 8; nt++) {
          const int col = wave * 128 + nt * 16 + l16;
          #pragma unroll
          for (int r = 0; r < 4; r++)
            h1s[(rb + r) * LDH + col] =
                __float2bfloat16(fast_tanh(acc[nt][r] + b1r[nt]));
        }
      }
      __syncthreads();
      // ---- L2: h2 = tanh(h1 @ W2 + b2), K = 1024 ----
      {
        f32x4 acc[8];
        #pragma unroll
        for (int i = 0; i < 8; i++) acc[i] = f32x4{0.f, 0.f, 0.f, 0.f};
        gemm_stream<32, 8, LDH>(h1s, W2p, Bst, wave, lane, l16, quad, acc);
        #pragma unroll
        for (int nt = 0; nt < 8; nt++) {
          const int col = wave * 128 + nt * 16 + l16;
          #pragma unroll
          for (int r = 0; r < 4; r++)
            h2s[(rb + r) * LDH + col] =
                __float2bfloat16(fast_tanh(acc[nt][r] + b2r[nt]));
        }
      }
      __syncthreads();
      // ---- L3: k = h2 @ W3 + b3, K = 1024; RK4 bookkeeping in registers ----
      {
        f32x4 acc[2];
        #pragma unroll
        for (int i = 0; i < 2; i++) acc[i] = f32x4{0.f, 0.f, 0.f, 0.f};
        gemm_stream<32, 2, LDH>(h2s, W3p, Bst, wave, lane, l16, quad, acc);
        #pragma unroll
        for (int nt = 0; nt < 2; nt++) {
          const int d = wave * 32 + nt * 16 + l16;
          #pragma unroll
          for (int r = 0; r < 4; r++) {
            const float kv = acc[nt][r] + b3r[nt];
            float uv;
            if (st4 == 0) {
              ab[nt][r] = kv;            uv = yreg[nt][r] + 0.5f * dtv * kv;
            } else if (st4 == 1) {
              ab[nt][r] += 2.f * kv;     uv = yreg[nt][r] + 0.5f * dtv * kv;
            } else if (st4 == 2) {
              ab[nt][r] += 2.f * kv;     uv = yreg[nt][r] + dtv * kv;
            } else {
              const float yn =
                  yreg[nt][r] + (dtv * (1.f / 6.f)) * (ab[nt][r] + kv);
              yreg[nt][r] = yn;
              uv = yn;                   // next timestep stage0: u = y
              store_out(out, ((size_t)(m0 + rb + r) * T_ + (t + 1)) * D_ + d,
                        yn, ofl);
            }
            uA[(rb + r) * LDU + d] = __float2bfloat16(uv);
          }
        }
      }
      __syncthreads();
    }
  }
}

// ---------------------------------------------------------------------------
extern "C" void kernel_launch(void* const* d_in, const int* in_sizes, int n_in,
                              void* d_out, int out_size, void* d_ws, size_t ws_size,
                              hipStream_t stream) {
  const void* fp   = d_in[0];
  const void* tarr = d_in[1];
  const void* W1   = d_in[2];
  const void* b1   = d_in[3];
  const void* W2   = d_in[4];
  const void* b2   = d_in[5];
  const void* W3   = d_in[6];
  const void* b3   = d_in[7];

  // workspace carve (~6.2 MB total, all bases 16B-aligned)
  char* ws = (char*)d_ws;
  __hip_bfloat16* W1p = (__hip_bfloat16*)ws; ws += (size_t)H_ * D_ * 2;
  __hip_bfloat16* W2p = (__hip_bfloat16*)ws; ws += (size_t)H_ * H_ * 2;
  __hip_bfloat16* W3p = (__hip_bfloat16*)ws; ws += (size_t)D_ * H_ * 2;
  __hip_bfloat16* W1t = (__hip_bfloat16*)ws; ws += (size_t)H_ * D_ * 2;
  __hip_bfloat16* W2t = (__hip_bfloat16*)ws; ws += (size_t)H_ * H_ * 2;
  __hip_bfloat16* W3t = (__hip_bfloat16*)ws; ws += (size_t)D_ * H_ * 2;
  float* bf1  = (float*)ws;                  ws += (size_t)H_ * 4;
  float* bf2  = (float*)ws;                  ws += (size_t)H_ * 4;
  float* bf3  = (float*)ws;                  ws += (size_t)D_ * 4;
  float* dts  = (float*)ws;                  ws += 64 * 4;
  int*   flags= (int*)ws;                    ws += 64 * 4;

  detect_k<<<1, 64, 0, stream>>>(tarr, W2, dts, flags, d_out);
  dim3 tb(32, 8);
  transpose_k<<<dim3(H_ / 32, D_ / 32), tb, 0, stream>>>(W1, W1t, D_, H_, flags);
  transpose_k<<<dim3(H_ / 32, H_ / 32), tb, 0, stream>>>(W2, W2t, H_, H_, flags);
  transpose_k<<<dim3(D_ / 32, H_ / 32), tb, 0, stream>>>(W3, W3t, H_, D_, flags);
  prep_bias_k<<<H_ / 256, 256, 0, stream>>>(b1, b2, b3, bf1, bf2, bf3, flags);
  pack_k<<<(H_ * D_ / 8) / 256, 256, 0, stream>>>(W1t, W1p, D_, 8);
  pack_k<<<(H_ * H_ / 8) / 256, 256, 0, stream>>>(W2t, W2p, H_, 8);
  pack_k<<<(D_ * H_ / 8) / 256, 256, 0, stream>>>(W3t, W3p, H_, 2);
  ode_k<<<M_ / 16, 512, 0, stream>>>(fp, W1p, W2p, W3p, bf1, bf2, bf3,
                                     dts, flags, d_out);
}

// Round 4
// 5424.819 us; speedup vs baseline: 6.3176x; 1.6284x over previous
//
#include <hip/hip_runtime.h>
#include <hip/hip_bf16.h>

// Problem constants (S,B,D,H,T) = (4,512,256,1024,50)
#define S_ 4
#define B_ 512
#define D_ 256
#define H_ 1024
#define T_ 50
#define M_ (S_*B_)   // 2048 rows total

#define LDH (H_ + 8)   // padded LDS row stride for h1/h2 (bf16 elems)
#define LDU (D_ + 8)   // padded LDS row stride for u

// Per-stage weight stream: 192 chunks x 16KB = 3MB  (W1:0-31, W2:32-159, W3:160-191)
#define NCHK 192
#define CHKB 16384

typedef __attribute__((ext_vector_type(8))) __bf16 bf16x8;
typedef __attribute__((ext_vector_type(4))) float  f32x4;

#define MFMA16(a, b, c) __builtin_amdgcn_mfma_f32_16x16x32_bf16(a, b, c, 0, 0, 0)
#define SB0() __builtin_amdgcn_sched_barrier(0)
// counted wait: keep 2 younger chunks (4 loads) in flight
#define VM4() do { asm volatile("s_waitcnt vmcnt(4)" ::: "memory"); SB0(); } while (0)
// retire all LDS reads (slot safe to overwrite by DMA)
#define LGSB() do { asm volatile("s_waitcnt lgkmcnt(0)" ::: "memory"); SB0(); } while (0)
// layer barrier WITHOUT vmcnt drain (prefetch stays in flight across it)
#define LBAR() do { SB0(); asm volatile("s_waitcnt lgkmcnt(0)" ::: "memory"); \
                    __builtin_amdgcn_s_barrier(); SB0(); } while (0)

__device__ __forceinline__ void gld16(const void* g, void* l) {
  // async global->LDS, 16B per lane. LDS dest = wave-uniform base (+lane*16 by HW).
  __builtin_amdgcn_global_load_lds(
      (const __attribute__((address_space(1))) void*)g,
      (__attribute__((address_space(3))) void*)l, 16, 0, 0);
}

// NaN-free fast tanh: saturates to +/-1, ~1e-6 abs error (<< bf16 eps)
__device__ __forceinline__ float fast_tanh(float x) {
  const float e = __expf(2.f * x);
  return 1.f - 2.f / (e + 1.f);
}

// non-temporal output store (keep 100MB traj stream from evicting the 3MB
// cyclic weight working set out of the per-XCD L2s)
__device__ __forceinline__ void store_out(void* out, size_t off, float v,
                                          int ofl) {
  if (ofl) {
    __builtin_nontemporal_store(v, (float*)out + off);
  } else {
    const unsigned short u =
        __builtin_bit_cast(unsigned short, __float2bfloat16(v));
    __builtin_nontemporal_store(u, (unsigned short*)out + off);
  }
}

// ---------------------------------------------------------------------------
// Runtime dtype detection + dt table + reg_state zeros.
//   flags[0] = weights/first_point/output are f32 (1) or bf16 (0)
//   flags[1] = time grid is f32 (1) or bf16 (0)
// ---------------------------------------------------------------------------
__global__ void detect_k(const void* t_raw, const void* w2_raw,
                         float* dts, int* flags, void* out) {
  __shared__ int cnt;
  const int l = threadIdx.x;           // 64 threads, 1 block
  if (l == 0) cnt = 0;
  __syncthreads();
  const unsigned short* u = (const unsigned short*)w2_raw;
  int c = 0;
  #pragma unroll
  for (int j = 0; j < 4; ++j) {
    const unsigned short v = u[l * 4 + j];
    const unsigned e = (v >> 7) & 0xFF;          // bf16 exponent field
    if (e >= 128) c++;                            // |x| >= 2.0 or NaN/Inf
  }
  atomicAdd(&cnt, c);
  __syncthreads();
  const unsigned tw0 = *(const unsigned*)t_raw;
  const int t_is_f32 = (tw0 == 0u) ? 1 : 0;
  const int w_is_f32 = (cnt > 16) ? 1 : 0;
  if (l == 0) { flags[0] = w_is_f32; flags[1] = t_is_f32; }
  if (l < T_ - 1) {
    float t0, t1;
    if (t_is_f32) {
      const float* tf = (const float*)t_raw;
      t0 = tf[l]; t1 = tf[l + 1];
    } else {
      const __hip_bfloat16* tb = (const __hip_bfloat16*)t_raw;
      t0 = __bfloat162float(tb[l]); t1 = __bfloat162float(tb[l + 1]);
    }
    dts[l] = t1 - t0;
  }
  if (l < S_) {   // reg_state = 0
    const size_t ro = (size_t)M_ * T_ * D_ + l;
    if (w_is_f32) ((float*)out)[ro] = 0.f;
    else          ((__hip_bfloat16*)out)[ro] = __float2bfloat16(0.f);
  }
}

// ---------------------------------------------------------------------------
// transpose to bf16: dst[N][K] = bf16(src[K][N]); src dtype per flags[0]
// ---------------------------------------------------------------------------
__global__ void transpose_k(const void* __restrict__ src,
                            __hip_bfloat16* __restrict__ dst, int K, int N,
                            const int* __restrict__ flags) {
  __shared__ __hip_bfloat16 tile[32][33];
  const int f32 = flags[0];
  const int tx = threadIdx.x, ty = threadIdx.y;
  const int nb = blockIdx.x * 32, kb = blockIdx.y * 32;
  #pragma unroll
  for (int j = 0; j < 32; j += 8) {
    const size_t si = (size_t)(kb + ty + j) * N + nb + tx;
    tile[ty + j][tx] = f32 ? __float2bfloat16(((const float*)src)[si])
                           : ((const __hip_bfloat16*)src)[si];
  }
  __syncthreads();
  #pragma unroll
  for (int j = 0; j < 32; j += 8)
    dst[(size_t)(nb + ty + j) * K + kb + tx] = tile[tx][ty + j];
}

// ---------------------------------------------------------------------------
// biases -> fp32 workspace arrays
// ---------------------------------------------------------------------------
__global__ void prep_bias_k(const void* b1r, const void* b2r, const void* b3r,
                            float* bf1, float* bf2, float* bf3,
                            const int* flags) {
  const int i = blockIdx.x * 256 + threadIdx.x;   // H_ threads
  const int f32 = flags[0];
  bf1[i] = f32 ? ((const float*)b1r)[i]
               : __bfloat162float(((const __hip_bfloat16*)b1r)[i]);
  bf2[i] = f32 ? ((const float*)b2r)[i]
               : __bfloat162float(((const __hip_bfloat16*)b2r)[i]);
  if (i < D_)
    bf3[i] = f32 ? ((const float*)b3r)[i]
                 : __bfloat162float(((const __hip_bfloat16*)b3r)[i]);
}

// ---------------------------------------------------------------------------
// pack Wt[N][K] (row-major bf16) into 16KB-chunk, WAVE-PRIVATE fragment stream.
// frag idx = c*1024 + w*128 + ntl*64 + lane  (16B per frag), ntl in {0,1}:
//   TPW==8 (L1/L2): chunk c -> kk = c>>2, tile nt = (c&3)*2 + ntl
//   TPW==2 (L3):    chunk c -> kk = c,    tile nt = ntl
// Fragment content (MFMA B layout), elems j of lane:
//   Wt[(w*TPW+nt)*16 + (lane&15)][kk*32 + (lane>>4)*8 + j]
// Wave w consumes exactly bytes [c*16K + w*2K, +2K) -- the same bytes wave w
// DMAs, so producer==consumer and no block barriers are needed.
// ---------------------------------------------------------------------------
__global__ void pack_k(const __hip_bfloat16* __restrict__ Wt,
                       __hip_bfloat16* __restrict__ P, int K, int TPW) {
  const int frag = blockIdx.x * 256 + threadIdx.x;   // one 16B fragment each
  const int lane = frag & 63;
  const int c    = frag >> 10;
  const int q    = frag & 1023;
  const int w    = q >> 7;
  const int ntl  = (q >> 6) & 1;
  int kk, nt;
  if (TPW == 8) { kk = c >> 2; nt = (c & 3) * 2 + ntl; }
  else          { kk = c;      nt = ntl; }
  const int n  = (w * TPW + nt) * 16 + (lane & 15);
  const int ko = kk * 32 + (lane >> 4) * 8;
  *(bf16x8*)&P[(size_t)frag * 8] = *(const bf16x8*)&Wt[(size_t)n * K + ko];
}

// ---------------------------------------------------------------------------
// Persistent ODE kernel: 128 blocks x 16 rows, 512 threads (8 waves).
// Each block integrates its 16 rows through all T-1 RK4 steps.
//   - u/h1/h2 activations in LDS; y/accb RK4 state in registers
//   - weights: one contiguous 3MB packed stream [W1|W2|W3] per stage, streamed
//     through a 4-slot x 16KB wave-private LDS ring via global_load_lds with
//     counted vmcnt (prefetch distance 3). ZERO barriers inside GEMMs; issues
//     wrap across layer/stage boundaries so the pipeline never drains.
//   - 3 raw (no-vmcnt-drain) barriers per stage, at layer boundaries only.
// LDS 137KB -> 1 block/CU; 8 waves = 2/SIMD.
// ---------------------------------------------------------------------------
__global__ __launch_bounds__(512, 2) void ode_k(
    const void* __restrict__ fp_raw,
    const __hip_bfloat16* __restrict__ Wall,   // packed [W1|W2|W3], 3MB
    const float* __restrict__ bf1, const float* __restrict__ bf2,
    const float* __restrict__ bf3, const float* __restrict__ dts,
    const int* __restrict__ flags, void* __restrict__ out) {
  __shared__ __hip_bfloat16 uA[16 * LDU];       //  8.2 KB
  __shared__ __hip_bfloat16 h1s[16 * LDH];      // 32.3 KB
  __shared__ __hip_bfloat16 h2s[16 * LDH];      // 32.3 KB
  __shared__ __hip_bfloat16 Bst[4 * 8192];      // 64   KB ring (4 x 16KB)

  const int tid = threadIdx.x;
  const int wave = tid >> 6, lane = tid & 63;
  const int l16 = lane & 15, quad = lane >> 4;
  const int m0 = blockIdx.x * 16;
  const int rb = quad * 4;                 // this lane's C-layout row base
  const int ofl = flags[0];

  // stream pointers (wave-private 2KB per 16KB chunk)
  const char* gw = (const char*)Wall + wave * 2048 + (size_t)lane * 16; // per-lane
  char* lb = (char*)Bst + wave * 2048;                 // wave-uniform DMA dest
  const char* bS = (const char*)Bst + wave * 2048 + (size_t)lane * 16;  // reads

  auto iss = [&](int tc) {                 // issue chunk tc (0..191), 2KB/wave
    const char* g_ = gw + (size_t)tc * CHKB;
    char* l_ = lb + (tc & 3) * CHKB;
    gld16(g_, l_);
    gld16(g_ + 1024, l_ + 1024);
  };

  // chunk pipeline step: wait chunk nc_ landed; read its 2 tiles; retire reads;
  // issue chunk nc_+3 (wrapping into next stage's stream).
  #define CHUNK(nc_, slot_, T0, T1)                                        \
    do {                                                                   \
      VM4();                                                               \
      T0 = *(const bf16x8*)(bS + (slot_) * CHKB);                          \
      T1 = *(const bf16x8*)(bS + (slot_) * CHKB + 1024);                   \
      LGSB();                                                              \
      { int tc_ = (nc_) + 3; if (tc_ >= NCHK) tc_ -= NCHK; iss(tc_); }     \
      SB0();                                                               \
    } while (0)

  // bias registers (match epilogue column mapping)
  float b1r[8], b2r[8], b3r[2];
  #pragma unroll
  for (int nt = 0; nt < 8; nt++) {
    b1r[nt] = bf1[wave * 128 + nt * 16 + l16];
    b2r[nt] = bf2[wave * 128 + nt * 16 + l16];
  }
  #pragma unroll
  for (int nt = 0; nt < 2; nt++) b3r[nt] = bf3[wave * 32 + nt * 16 + l16];

  // RK4 state in registers at this lane's L3 C-layout positions:
  //   (m = m0 + rb + r, d = wave*32 + nt*16 + l16)
  float yreg[2][4], ab[2][4];
  #pragma unroll
  for (int nt = 0; nt < 2; nt++) {
    const int d = wave * 32 + nt * 16 + l16;
    #pragma unroll
    for (int r = 0; r < 4; r++) {
      const int m = m0 + rb + r;
      const size_t si = (size_t)m * D_ + d;
      const float v = ofl ? ((const float*)fp_raw)[si]
                          : __bfloat162float(((const __hip_bfloat16*)fp_raw)[si]);
      yreg[nt][r] = v;
      ab[nt][r] = 0.f;
      uA[(rb + r) * LDU + d] = __float2bfloat16(v);   // stage0 u = y
      store_out(out, ((size_t)m * T_) * D_ + d, v, ofl);  // traj[t=0] = y
    }
  }
  // prime the ring: chunks 0,1,2 in flight (6 loads)
  iss(0); iss(1); iss(2);
  LBAR();

  #pragma unroll 1
  for (int t = 0; t < T_ - 1; ++t) {
    const float dtv = dts[t];
    #pragma unroll 1
    for (int st4 = 0; st4 < 4; ++st4) {
      // ---- L1: h1 = tanh(u @ W1 + b1), K=256, chunks 0..31 ----
      {
        f32x4 acc[8];
        #pragma unroll
        for (int i = 0; i < 8; i++) acc[i] = f32x4{0.f, 0.f, 0.f, 0.f};
        #pragma unroll 1
        for (int kk = 0; kk < 8; ++kk) {
          const bf16x8 aF = *(const bf16x8*)&uA[l16 * LDU + kk * 32 + quad * 8];
          const int nc = kk * 4;
          bf16x8 t0, t1;
          CHUNK(nc + 0, 0, t0, t1);
          acc[0] = MFMA16(aF, t0, acc[0]); acc[1] = MFMA16(aF, t1, acc[1]);
          CHUNK(nc + 1, 1, t0, t1);
          acc[2] = MFMA16(aF, t0, acc[2]); acc[3] = MFMA16(aF, t1, acc[3]);
          CHUNK(nc + 2, 2, t0, t1);
          acc[4] = MFMA16(aF, t0, acc[4]); acc[5] = MFMA16(aF, t1, acc[5]);
          CHUNK(nc + 3, 3, t0, t1);
          acc[6] = MFMA16(aF, t0, acc[6]); acc[7] = MFMA16(aF, t1, acc[7]);
        }
        #pragma unroll
        for (int nt = 0; nt < 8; nt++) {
          const int col = wave * 128 + nt * 16 + l16;
          #pragma unroll
          for (int r = 0; r < 4; r++)
            h1s[(rb + r) * LDH + col] =
                __float2bfloat16(fast_tanh(acc[nt][r] + b1r[nt]));
        }
      }
      LBAR();
      // ---- L2: h2 = tanh(h1 @ W2 + b2), K=1024, chunks 32..159 ----
      {
        f32x4 acc[8];
        #pragma unroll
        for (int i = 0; i < 8; i++) acc[i] = f32x4{0.f, 0.f, 0.f, 0.f};
        #pragma unroll 1
        for (int kk = 0; kk < 32; ++kk) {
          const bf16x8 aF = *(const bf16x8*)&h1s[l16 * LDH + kk * 32 + quad * 8];
          const int nc = 32 + kk * 4;
          bf16x8 t0, t1;
          CHUNK(nc + 0, 0, t0, t1);
          acc[0] = MFMA16(aF, t0, acc[0]); acc[1] = MFMA16(aF, t1, acc[1]);
          CHUNK(nc + 1, 1, t0, t1);
          acc[2] = MFMA16(aF, t0, acc[2]); acc[3] = MFMA16(aF, t1, acc[3]);
          CHUNK(nc + 2, 2, t0, t1);
          acc[4] = MFMA16(aF, t0, acc[4]); acc[5] = MFMA16(aF, t1, acc[5]);
          CHUNK(nc + 3, 3, t0, t1);
          acc[6] = MFMA16(aF, t0, acc[6]); acc[7] = MFMA16(aF, t1, acc[7]);
        }
        #pragma unroll
        for (int nt = 0; nt < 8; nt++) {
          const int col = wave * 128 + nt * 16 + l16;
          #pragma unroll
          for (int r = 0; r < 4; r++)
            h2s[(rb + r) * LDH + col] =
                __float2bfloat16(fast_tanh(acc[nt][r] + b2r[nt]));
        }
      }
      LBAR();
      // ---- L3: k = h2 @ W3 + b3, K=1024, chunks 160..191 (kk = chunk) ----
      {
        f32x4 acc[2];
        acc[0] = f32x4{0.f, 0.f, 0.f, 0.f};
        acc[1] = f32x4{0.f, 0.f, 0.f, 0.f};
        #pragma unroll 1
        for (int c3 = 0; c3 < 32; c3 += 4) {
          const int nc = 160 + c3;
          bf16x8 t0, t1;
          CHUNK(nc + 0, 0, t0, t1);
          { const bf16x8 aF =
                *(const bf16x8*)&h2s[l16 * LDH + (c3 + 0) * 32 + quad * 8];
            acc[0] = MFMA16(aF, t0, acc[0]); acc[1] = MFMA16(aF, t1, acc[1]); }
          CHUNK(nc + 1, 1, t0, t1);
          { const bf16x8 aF =
                *(const bf16x8*)&h2s[l16 * LDH + (c3 + 1) * 32 + quad * 8];
            acc[0] = MFMA16(aF, t0, acc[0]); acc[1] = MFMA16(aF, t1, acc[1]); }
          CHUNK(nc + 2, 2, t0, t1);
          { const bf16x8 aF =
                *(const bf16x8*)&h2s[l16 * LDH + (c3 + 2) * 32 + quad * 8];
            acc[0] = MFMA16(aF, t0, acc[0]); acc[1] = MFMA16(aF, t1, acc[1]); }
          CHUNK(nc + 3, 3, t0, t1);
          { const bf16x8 aF =
                *(const bf16x8*)&h2s[l16 * LDH + (c3 + 3) * 32 + quad * 8];
            acc[0] = MFMA16(aF, t0, acc[0]); acc[1] = MFMA16(aF, t1, acc[1]); }
        }
        // RK4 bookkeeping in registers + traj store + next-u build
        #pragma unroll
        for (int nt = 0; nt < 2; nt++) {
          const int d = wave * 32 + nt * 16 + l16;
          #pragma unroll
          for (int r = 0; r < 4; r++) {
            const float kv = acc[nt][r] + b3r[nt];
            float uv;
            if (st4 == 0) {
              ab[nt][r] = kv;            uv = yreg[nt][r] + 0.5f * dtv * kv;
            } else if (st4 == 1) {
              ab[nt][r] += 2.f * kv;     uv = yreg[nt][r] + 0.5f * dtv * kv;
            } else if (st4 == 2) {
              ab[nt][r] += 2.f * kv;     uv = yreg[nt][r] + dtv * kv;
            } else {
              const float yn =
                  yreg[nt][r] + (dtv * (1.f / 6.f)) * (ab[nt][r] + kv);
              yreg[nt][r] = yn;
              uv = yn;                   // next timestep stage0: u = y
              store_out(out, ((size_t)(m0 + rb + r) * T_ + (t + 1)) * D_ + d,
                        yn, ofl);
            }
            uA[(rb + r) * LDU + d] = __float2bfloat16(uv);
          }
        }
      }
      LBAR();
    }
  }
  #undef CHUNK
}

// ---------------------------------------------------------------------------
extern "C" void kernel_launch(void* const* d_in, const int* in_sizes, int n_in,
                              void* d_out, int out_size, void* d_ws, size_t ws_size,
                              hipStream_t stream) {
  const void* fp   = d_in[0];
  const void* tarr = d_in[1];
  const void* W1   = d_in[2];
  const void* b1   = d_in[3];
  const void* W2   = d_in[4];
  const void* b2   = d_in[5];
  const void* W3   = d_in[6];
  const void* b3   = d_in[7];

  // workspace carve (~6.2 MB total, all bases 16B-aligned).
  // W1p|W2p|W3p MUST stay contiguous in this order: they form the 3MB
  // per-stage chunk stream [chunks 0..31 | 32..159 | 160..191].
  char* ws = (char*)d_ws;
  __hip_bfloat16* W1p = (__hip_bfloat16*)ws; ws += (size_t)H_ * D_ * 2;
  __hip_bfloat16* W2p = (__hip_bfloat16*)ws; ws += (size_t)H_ * H_ * 2;
  __hip_bfloat16* W3p = (__hip_bfloat16*)ws; ws += (size_t)D_ * H_ * 2;
  __hip_bfloat16* W1t = (__hip_bfloat16*)ws; ws += (size_t)H_ * D_ * 2;
  __hip_bfloat16* W2t = (__hip_bfloat16*)ws; ws += (size_t)H_ * H_ * 2;
  __hip_bfloat16* W3t = (__hip_bfloat16*)ws; ws += (size_t)D_ * H_ * 2;
  float* bf1  = (float*)ws;                  ws += (size_t)H_ * 4;
  float* bf2  = (float*)ws;                  ws += (size_t)H_ * 4;
  float* bf3  = (float*)ws;                  ws += (size_t)D_ * 4;
  float* dts  = (float*)ws;                  ws += 64 * 4;
  int*   flags= (int*)ws;                    ws += 64 * 4;

  detect_k<<<1, 64, 0, stream>>>(tarr, W2, dts, flags, d_out);
  dim3 tb(32, 8);
  transpose_k<<<dim3(H_ / 32, D_ / 32), tb, 0, stream>>>(W1, W1t, D_, H_, flags);
  transpose_k<<<dim3(H_ / 32, H_ / 32), tb, 0, stream>>>(W2, W2t, H_, H_, flags);
  transpose_k<<<dim3(D_ / 32, H_ / 32), tb, 0, stream>>>(W3, W3t, H_, D_, flags);
  prep_bias_k<<<H_ / 256, 256, 0, stream>>>(b1, b2, b3, bf1, bf2, bf3, flags);
  pack_k<<<(H_ * D_ / 8) / 256, 256, 0, stream>>>(W1t, W1p, D_, 8);
  pack_k<<<(H_ * H_ / 8) / 256, 256, 0, stream>>>(W2t, W2p, H_, 8);
  pack_k<<<(D_ * H_ / 8) / 256, 256, 0, stream>>>(W3t, W3p, H_, 2);
  ode_k<<<M_ / 16, 512, 0, stream>>>(fp, W1p, bf1, bf2, bf3, dts, flags, d_out);
}